// Round 6
// baseline (126.784 us; speedup 1.0000x reference)
//
#include <hip/hip_runtime.h>

#define BQ   16
#define QLEN 128
#define KLEN 512
#define HD   256
#define VD   256

typedef __bf16 bf16x8 __attribute__((ext_vector_type(8)));
typedef __bf16 bf16x4 __attribute__((ext_vector_type(4)));
typedef float  f32x4  __attribute__((ext_vector_type(4)));

static __device__ __forceinline__ float fexp2(float x) {
#if __has_builtin(__builtin_amdgcn_exp2f)
    return __builtin_amdgcn_exp2f(x);
#else
    return exp2f(x);
#endif
}
static __device__ __forceinline__ float frcp(float x) {
#if __has_builtin(__builtin_amdgcn_rcpf)
    return __builtin_amdgcn_rcpf(x);
#else
    return 1.0f / x;
#endif
}

#define EXP_SCALE 2.8853900817779268f   // 2*log2(e)

// ---------------- MFMA projection GEMM (split-bf16, ~fp32 accurate) ----
// C[r][h] = sum_d A[r][d]*W[h][d];  E = exp2(EXP_SCALE * C).
// grid (2, 160): by<32 -> queries -> Eq row-major; else keys -> Ekt
// transposed [b][h][k]. Fully-masked 64-key-row blocks exit immediately
// (Ekt stays poisoned there; softmax zeroes those k exactly).
// W split to bf16 hi/lo inline. a*w ~= hi*Whi + hi*Wlo + lo*Whi.
__global__ __launch_bounds__(256) void mfma_proj(
    const float* __restrict__ queries, const float* __restrict__ keys,
    const float* __restrict__ Wq, const float* __restrict__ Wk,
    const int* __restrict__ vlen,
    float* __restrict__ Eq, float* __restrict__ Ekt)
{
    __shared__ __bf16 Ahi_s[64][40];    // stride 40 bf16 = 80 B: 2-way max
    __shared__ __bf16 Alo_s[64][40];
    __shared__ __bf16 Whi_s[128][40];
    __shared__ __bf16 Wlo_s[128][40];

    const int t    = threadIdx.x;
    const int ln   = t & 63;
    const int w    = t >> 6;
    const int p    = ln & 15;
    const int quad = ln >> 4;
    const int bx = blockIdx.x, by = blockIdx.y;
    const bool isq = by < 32;
    const int row0 = by * 64;
    const int col0 = bx * 128;

    if (!isq) {   // block-uniform masked-key skip
        const int kr0 = row0 - 2048;
        if ((kr0 & 511) >= vlen[kr0 >> 9]) return;
    }

    const float* Ag = isq ? (queries + (size_t)row0 * HD)
                          : (keys + (size_t)(row0 - 2048) * HD);
    const float* Wg = isq ? Wq : Wk;

    const int ar = t >> 2, ac = (t & 3) * 8;     // A stage: 8 floats/thread
    const int wr = t >> 1, wc = (t & 1) * 16;    // W stage: 16 floats/thread

    float4 pa0, pa1, pw0, pw1, pw2, pw3;
    {
        const float* ap = Ag + ar * HD + ac;
        pa0 = *(const float4*)ap;
        pa1 = *(const float4*)(ap + 4);
        const float* wp = Wg + (size_t)(col0 + wr) * HD + wc;
        pw0 = *(const float4*)wp;       pw1 = *(const float4*)(wp + 4);
        pw2 = *(const float4*)(wp + 8); pw3 = *(const float4*)(wp + 12);
    }

    f32x4 acc[4][2] = {};

    for (int s = 0; s < 8; ++s) {
        __syncthreads();
        {
            float fa[8] = {pa0.x, pa0.y, pa0.z, pa0.w, pa1.x, pa1.y, pa1.z, pa1.w};
            bf16x8 h, l;
            #pragma unroll
            for (int j = 0; j < 8; ++j) {
                __bf16 hv = (__bf16)fa[j];
                h[j] = hv;
                l[j] = (__bf16)(fa[j] - (float)hv);
            }
            *(bf16x8*)&Ahi_s[ar][ac] = h;
            *(bf16x8*)&Alo_s[ar][ac] = l;

            float fw[16] = {pw0.x, pw0.y, pw0.z, pw0.w, pw1.x, pw1.y, pw1.z, pw1.w,
                            pw2.x, pw2.y, pw2.z, pw2.w, pw3.x, pw3.y, pw3.z, pw3.w};
            bf16x8 wh0, wh1, wl0, wl1;
            #pragma unroll
            for (int j = 0; j < 8; ++j) {
                __bf16 hv = (__bf16)fw[j];
                wh0[j] = hv;
                wl0[j] = (__bf16)(fw[j] - (float)hv);
                __bf16 hv1 = (__bf16)fw[8 + j];
                wh1[j] = hv1;
                wl1[j] = (__bf16)(fw[8 + j] - (float)hv1);
            }
            *(bf16x8*)&Whi_s[wr][wc]     = wh0;
            *(bf16x8*)&Whi_s[wr][wc + 8] = wh1;
            *(bf16x8*)&Wlo_s[wr][wc]     = wl0;
            *(bf16x8*)&Wlo_s[wr][wc + 8] = wl1;
        }
        __syncthreads();
        if (s < 7) {   // prefetch next K-slab
            const int kc = (s + 1) * 32;
            const float* ap = Ag + ar * HD + kc + ac;
            pa0 = *(const float4*)ap;
            pa1 = *(const float4*)(ap + 4);
            const float* wp = Wg + (size_t)(col0 + wr) * HD + kc + wc;
            pw0 = *(const float4*)wp;       pw1 = *(const float4*)(wp + 4);
            pw2 = *(const float4*)(wp + 8); pw3 = *(const float4*)(wp + 12);
        }
        bf16x8 ah[4], al[4], bh[2], bl[2];
        #pragma unroll
        for (int mi = 0; mi < 4; ++mi) {
            ah[mi] = *(const bf16x8*)&Ahi_s[mi * 16 + p][quad * 8];
            al[mi] = *(const bf16x8*)&Alo_s[mi * 16 + p][quad * 8];
        }
        #pragma unroll
        for (int ci = 0; ci < 2; ++ci) {
            const int hrow = w * 32 + ci * 16 + p;
            bh[ci] = *(const bf16x8*)&Whi_s[hrow][quad * 8];
            bl[ci] = *(const bf16x8*)&Wlo_s[hrow][quad * 8];
        }
        #pragma unroll
        for (int mi = 0; mi < 4; ++mi)
            #pragma unroll
            for (int ci = 0; ci < 2; ++ci) {
                acc[mi][ci] = __builtin_amdgcn_mfma_f32_16x16x32_bf16(ah[mi], bh[ci], acc[mi][ci], 0, 0, 0);
                acc[mi][ci] = __builtin_amdgcn_mfma_f32_16x16x32_bf16(ah[mi], bl[ci], acc[mi][ci], 0, 0, 0);
                acc[mi][ci] = __builtin_amdgcn_mfma_f32_16x16x32_bf16(al[mi], bh[ci], acc[mi][ci], 0, 0, 0);
            }
    }

    // epilogue: C/D layout col=lane&15, row=quad*4+reg
    #pragma unroll
    for (int mi = 0; mi < 4; ++mi)
        #pragma unroll
        for (int ci = 0; ci < 2; ++ci) {
            const int H  = col0 + w * 32 + ci * 16 + p;
            const int rl = mi * 16 + quad * 4;
            float e0 = fexp2(acc[mi][ci][0] * EXP_SCALE);
            float e1 = fexp2(acc[mi][ci][1] * EXP_SCALE);
            float e2 = fexp2(acc[mi][ci][2] * EXP_SCALE);
            float e3 = fexp2(acc[mi][ci][3] * EXP_SCALE);
            if (isq) {
                float* dst = Eq + (size_t)(row0 + rl) * HD + H;
                dst[0] = e0; dst[HD] = e1; dst[2 * HD] = e2; dst[3 * HD] = e3;
            } else {
                const int kr = row0 - 2048 + rl;
                const int b = kr >> 9, k0 = kr & 511;
                float4 st; st.x = e0; st.y = e1; st.z = e2; st.w = e3;
                *(float4*)(Ekt + ((size_t)b * HD + H) * KLEN + k0) = st;
            }
        }
}

// ---------------- fallback fp32 projection (if ws too small) ----------
__global__ __launch_bounds__(256) void proj_exp_gemm(
    const float* __restrict__ Qin, const float* __restrict__ Kin,
    const float* __restrict__ Wq, const float* __restrict__ Wk,
    float* __restrict__ Eq, float* __restrict__ Ekt)
{
    __shared__ union {
        struct { float a[2][16][68]; float w[2][16][68]; } s;
        float tb[64][65];
    } sh;

    const int t  = threadIdx.x;
    const int tx = t & 15, ty = t >> 4;
    const int bx = blockIdx.x, by = blockIdx.y;
    const bool isq = by < 32;
    const int row0 = isq ? by * 64 : (by - 32) * 64;
    const float* A = isq ? Qin : Kin;
    const float* W = isq ? Wq : Wk;
    const int lrow = t >> 2, ld0 = (t & 3) * 4;
    const float* Ab = A + (row0 + lrow) * HD;
    const float* Wb = W + (bx * 64 + lrow) * HD;

    float4 av = *(const float4*)(Ab + ld0);
    float4 wv = *(const float4*)(Wb + ld0);
    sh.s.a[0][ld0 + 0][lrow] = av.x; sh.s.a[0][ld0 + 1][lrow] = av.y;
    sh.s.a[0][ld0 + 2][lrow] = av.z; sh.s.a[0][ld0 + 3][lrow] = av.w;
    sh.s.w[0][ld0 + 0][lrow] = wv.x; sh.s.w[0][ld0 + 1][lrow] = wv.y;
    sh.s.w[0][ld0 + 2][lrow] = wv.z; sh.s.w[0][ld0 + 3][lrow] = wv.w;

    float acc[4][4] = {};
    int p = 0;
    for (int kc = 0; kc < HD; kc += 16) {
        if (kc + 16 < HD) {
            av = *(const float4*)(Ab + kc + 16 + ld0);
            wv = *(const float4*)(Wb + kc + 16 + ld0);
        }
        __syncthreads();
        if (kc + 16 < HD) {
            const int np = p ^ 1;
            sh.s.a[np][ld0 + 0][lrow] = av.x; sh.s.a[np][ld0 + 1][lrow] = av.y;
            sh.s.a[np][ld0 + 2][lrow] = av.z; sh.s.a[np][ld0 + 3][lrow] = av.w;
            sh.s.w[np][ld0 + 0][lrow] = wv.x; sh.s.w[np][ld0 + 1][lrow] = wv.y;
            sh.s.w[np][ld0 + 2][lrow] = wv.z; sh.s.w[np][ld0 + 3][lrow] = wv.w;
        }
        #pragma unroll
        for (int dd = 0; dd < 16; ++dd) {
            float4 a4 = *(const float4*)&sh.s.a[p][dd][ty * 4];
            float4 w4 = *(const float4*)&sh.s.w[p][dd][tx * 4];
            const float* af = (const float*)&a4;
            const float* wf = (const float*)&w4;
            #pragma unroll
            for (int i = 0; i < 4; ++i)
                #pragma unroll
                for (int j = 0; j < 4; ++j)
                    acc[i][j] = fmaf(af[i], wf[j], acc[i][j]);
        }
        p ^= 1;
    }

    float e[4][4];
    #pragma unroll
    for (int i = 0; i < 4; ++i)
        #pragma unroll
        for (int j = 0; j < 4; ++j)
            e[i][j] = fexp2(acc[i][j] * EXP_SCALE);

    if (isq) {
        float* Cb = Eq + (row0 + ty * 4) * HD + bx * 64 + tx * 4;
        #pragma unroll
        for (int i = 0; i < 4; ++i) {
            float4 st; st.x = e[i][0]; st.y = e[i][1]; st.z = e[i][2]; st.w = e[i][3];
            *(float4*)(Cb + i * HD) = st;
        }
    } else {
        __syncthreads();
        #pragma unroll
        for (int j = 0; j < 4; ++j) {
            float4 st; st.x = e[0][j]; st.y = e[1][j]; st.z = e[2][j]; st.w = e[3][j];
            *(float4*)&sh.tb[tx * 4 + j][ty * 4] = st;
        }
        __syncthreads();
        const int r = t >> 2, c0 = (t & 3) * 16;
        const int b = row0 >> 9, kbase = row0 & 511;
        float* dst = Ekt + ((size_t)b * HD + bx * 64 + r) * KLEN + kbase + c0;
        #pragma unroll
        for (int u = 0; u < 4; ++u) {
            float4 v = *(const float4*)&sh.tb[r][c0 + u * 4];
            *(float4*)(dst + u * 4) = v;
        }
    }
}

// ---------------- fused scores + masked softmax + PV ------------------
// grid 1024: blk = qtile*16 + b (qtile = 64 tiles of 2 queries).
// XCD (blk%8) = b%8 serves batches {x, x+8}: Ekt+values+Eq slabs fit L2.
// 4 blocks/CU co-resident (LDS ~23 KB, VGPR<=64) -> 32 waves/CU.
// Wave-uniform skipping of fully-masked k-ranges.
__global__ __launch_bounds__(512, 8) void fused_attn(
    const float* __restrict__ Eq, const float* __restrict__ Ekt,
    const float* __restrict__ values, const float* __restrict__ Wv,
    const int* __restrict__ vlen, float* __restrict__ out)
{
    __shared__ float eq_s[2][HD];
    __shared__ float wv_s[HD];
    __shared__ float sc[2][KLEN];
    __shared__ float ps[4][2][KLEN];   // phase-1 partials; aliased as po[8][2][VD]
    __shared__ float wred[4];

    const int t    = threadIdx.x;
    const int b    = blockIdx.x & 15;
    const int q0   = (blockIdx.x >> 4) * 2;
    const int lane = t & 63;
    const int wid  = t >> 6;
    const int len  = vlen[b];

    {
        const int h = t & 255, rr = t >> 8;
        eq_s[rr][h] = Eq[(b * QLEN + q0 + rr) * HD + h];
        if (t < HD) {
            float w = Wv[t];
            wv_s[t] = w;
            float ws = w;
            #pragma unroll
            for (int off = 32; off > 0; off >>= 1) ws += __shfl_xor(ws, off, 64);
            if (lane == 0) wred[wid] = ws;
        }
    }
    __syncthreads();
    const float wv_sum = wred[0] + wred[1] + wred[2] + wred[3];

    // ---- Phase 1: scores. Wave = (h-slice, k-half); skip masked k-half.
    const int hs    = wid & 3, khalf = wid >> 2;
    if (khalf * 256 < len) {
        const int hbase = hs * 64;
        const int k4    = khalf * 256 + lane * 4;
        const float* ek = Ekt + ((size_t)b * HD + hbase) * KLEN + k4;
        float acc[2][4] = {};
        for (int hh = 0; hh < 64; hh += 4) {
            float4 e0 = *(const float4*)(ek + (size_t)(hh + 0) * KLEN);
            float4 e1 = *(const float4*)(ek + (size_t)(hh + 1) * KLEN);
            float4 e2 = *(const float4*)(ek + (size_t)(hh + 2) * KLEN);
            float4 e3 = *(const float4*)(ek + (size_t)(hh + 3) * KLEN);
            const float* E0 = (const float*)&e0;
            const float* E1 = (const float*)&e1;
            const float* E2 = (const float*)&e2;
            const float* E3 = (const float*)&e3;
            const float w0 = wv_s[hbase + hh + 0], w1 = wv_s[hbase + hh + 1];
            const float w2 = wv_s[hbase + hh + 2], w3 = wv_s[hbase + hh + 3];
            #pragma unroll
            for (int i = 0; i < 2; ++i) {
                const float a0 = eq_s[i][hbase + hh + 0], a1 = eq_s[i][hbase + hh + 1];
                const float a2 = eq_s[i][hbase + hh + 2], a3 = eq_s[i][hbase + hh + 3];
                #pragma unroll
                for (int j = 0; j < 4; ++j) {
                    float d0 = fmaf(a0, E0[j], 1.f);
                    float d1 = fmaf(a1, E1[j], 1.f);
                    float d2 = fmaf(a2, E2[j], 1.f);
                    float d3 = fmaf(a3, E3[j], 1.f);
                    float d01 = d0 * d1, d23 = d2 * d3;
                    float n01 = fmaf(w1, d0, w0 * d1);
                    float n23 = fmaf(w3, d2, w2 * d3);
                    float top = fmaf(n23, d01, n01 * d23);
                    acc[i][j] = fmaf(top, frcp(d01 * d23), acc[i][j]);
                }
            }
        }
        #pragma unroll
        for (int i = 0; i < 2; ++i) {
            float4 st; st.x = acc[i][0]; st.y = acc[i][1]; st.z = acc[i][2]; st.w = acc[i][3];
            *(float4*)&ps[hs][i][k4] = st;
        }
    }
    __syncthreads();

    {   // reduce 4 h-slices (garbage for masked k: zeroed by softmax below)
        const int q = t >> 8, kk = (t & 255) * 2;
        float2 s0 = *(const float2*)&ps[0][q][kk];
        float2 s1 = *(const float2*)&ps[1][q][kk];
        float2 s2 = *(const float2*)&ps[2][q][kk];
        float2 s3 = *(const float2*)&ps[3][q][kk];
        float2 r;
        r.x = fmaf(-2.f, s0.x + s1.x + s2.x + s3.x, wv_sum);
        r.y = fmaf(-2.f, s0.y + s1.y + s2.y + s3.y, wv_sum);
        *(float2*)&sc[q][kk] = r;
    }
    __syncthreads();

    // ---- Phase 2: masked softmax, wave w (w<2) handles row w.
    if (wid < 2) {
        float s[8];
        float m = -3.0e38f;
        #pragma unroll
        for (int j = 0; j < 8; ++j) {
            int k = lane + j * 64;
            float v = sc[wid][k];
            v = (k < len) ? v : -1.0e6f;
            s[j] = v;
            m = fmaxf(m, v);
        }
        #pragma unroll
        for (int off = 32; off > 0; off >>= 1) m = fmaxf(m, __shfl_xor(m, off, 64));
        float sum = 0.f;
        #pragma unroll
        for (int j = 0; j < 8; ++j) {
            float ev = fexp2(1.4426950408889634f * (s[j] - m));
            s[j] = ev;
            sum += ev;
        }
        #pragma unroll
        for (int off = 32; off > 0; off >>= 1) sum += __shfl_xor(sum, off, 64);
        const float rs = frcp(sum);
        #pragma unroll
        for (int j = 0; j < 8; ++j) sc[wid][lane + j * 64] = s[j] * rs;
    }
    __syncthreads();

    // ---- Phase 3: PV, k-sliced; skip fully-masked slices (zero partials).
    float (*po)[2][VD] = (float (*)[2][VD])ps;
    const int c4 = lane * 4;
    if (wid * 64 < len) {
        const float* vb = values + (size_t)b * KLEN * VD + (size_t)(wid * 64) * VD + c4;
        float o[2][4] = {};
        for (int kk = 0; kk < 64; kk += 4) {
            const int k = wid * 64 + kk;
            float4 pr[2];
            pr[0] = *(const float4*)&sc[0][k];
            pr[1] = *(const float4*)&sc[1][k];
            #pragma unroll
            for (int j = 0; j < 4; ++j) {
                float4 v4 = *(const float4*)(vb + (size_t)(kk + j) * VD);
                #pragma unroll
                for (int r = 0; r < 2; ++r) {
                    float pj = ((const float*)&pr[r])[j];
                    o[r][0] = fmaf(pj, v4.x, o[r][0]);
                    o[r][1] = fmaf(pj, v4.y, o[r][1]);
                    o[r][2] = fmaf(pj, v4.z, o[r][2]);
                    o[r][3] = fmaf(pj, v4.w, o[r][3]);
                }
            }
        }
        #pragma unroll
        for (int r = 0; r < 2; ++r) {
            float4 st; st.x = o[r][0]; st.y = o[r][1]; st.z = o[r][2]; st.w = o[r][3];
            *(float4*)&po[wid][r][c4] = st;
        }
    } else {
        float4 z; z.x = z.y = z.z = z.w = 0.f;
        #pragma unroll
        for (int r = 0; r < 2; ++r) *(float4*)&po[wid][r][c4] = z;
    }
    __syncthreads();

    {   // reduce 8 k-slices -> output (512 outputs, 1/thread)
        const int r = t >> 8, c = t & 255;
        float s = 0.f;
        #pragma unroll
        for (int sl = 0; sl < 8; ++sl) s += po[sl][r][c];
        out[(b * QLEN + q0 + r) * VD + c] = s;
    }
}

extern "C" void kernel_launch(void* const* d_in, const int* in_sizes, int n_in,
                              void* d_out, int out_size, void* d_ws, size_t ws_size,
                              hipStream_t stream) {
    const float* queries = (const float*)d_in[0];
    const float* keys    = (const float*)d_in[1];
    const float* values  = (const float*)d_in[2];
    const float* Wq      = (const float*)d_in[3];
    const float* Wk      = (const float*)d_in[4];
    const float* Wv      = (const float*)d_in[5];
    const int*   vl      = (const int*)d_in[6];
    float* out = (float*)d_out;

    float* Eq  = (float*)d_ws;                 // [2048][256]        (2 MB)
    float* Ekt = Eq + 2048 * 256;              // [16][256][512]     (8 MB)

    if (ws_size >= 10485760) {
        mfma_proj<<<dim3(2, 160), 256, 0, stream>>>(queries, keys, Wq, Wk, vl, Eq, Ekt);
    } else {
        proj_exp_gemm<<<dim3(4, 160), 256, 0, stream>>>(queries, keys, Wq, Wk, Eq, Ekt);
    }
    fused_attn<<<dim3(1024), 512, 0, stream>>>(Eq, Ekt, values, Wv, vl, out);
}

// Round 7
// 116.375 us; speedup vs baseline: 1.0894x; 1.0894x over previous
//
#include <hip/hip_runtime.h>

#define BQ   16
#define QLEN 128
#define KLEN 512
#define HD   256
#define VD   256

typedef __bf16 bf16x8 __attribute__((ext_vector_type(8)));
typedef float  f32x4  __attribute__((ext_vector_type(4)));

static __device__ __forceinline__ float fexp2(float x) {
#if __has_builtin(__builtin_amdgcn_exp2f)
    return __builtin_amdgcn_exp2f(x);
#else
    return exp2f(x);
#endif
}
static __device__ __forceinline__ float frcp(float x) {
#if __has_builtin(__builtin_amdgcn_rcpf)
    return __builtin_amdgcn_rcpf(x);
#else
    return 1.0f / x;
#endif
}

#define EXP_SCALE 2.8853900817779268f   // 2*log2(e)

// ---------------- MFMA projection GEMM (split-bf16, ~fp32 accurate) ----
// 64x64 tiles -> grid (4, 160) = 640 blocks (2.5 blocks/CU) for latency
// hiding; previous 64x128/320-block version was occupancy-starved.
// by<32 -> queries -> Eq row-major; else keys -> Ekt transposed [b][h][k].
// Fully-masked 64-key-row blocks exit immediately (softmax zeroes them).
// W split to bf16 hi/lo inline. a*w ~= hi*Whi + hi*Wlo + lo*Whi.
__global__ __launch_bounds__(256) void mfma_proj(
    const float* __restrict__ queries, const float* __restrict__ keys,
    const float* __restrict__ Wq, const float* __restrict__ Wk,
    const int* __restrict__ vlen,
    float* __restrict__ Eq, float* __restrict__ Ekt)
{
    __shared__ __bf16 Ahi_s[64][40];    // stride 40 bf16 = 80 B: 2-way max
    __shared__ __bf16 Alo_s[64][40];
    __shared__ __bf16 Whi_s[64][40];
    __shared__ __bf16 Wlo_s[64][40];

    const int t    = threadIdx.x;
    const int ln   = t & 63;
    const int w    = t >> 6;
    const int p    = ln & 15;
    const int quad = ln >> 4;
    const int bx = blockIdx.x, by = blockIdx.y;
    const bool isq = by < 32;
    const int row0 = by * 64;
    const int col0 = bx * 64;

    if (!isq) {   // block-uniform masked-key skip
        const int kr0 = row0 - 2048;
        if ((kr0 & 511) >= vlen[kr0 >> 9]) return;
    }

    const float* Ag = isq ? (queries + (size_t)row0 * HD)
                          : (keys + (size_t)(row0 - 2048) * HD);
    const float* Wg = isq ? Wq : Wk;

    const int ar = t >> 2, ac = (t & 3) * 8;     // 8 floats/thread for A and W

    float4 pa0, pa1, pw0, pw1;
    {
        const float* ap = Ag + ar * HD + ac;
        pa0 = *(const float4*)ap;
        pa1 = *(const float4*)(ap + 4);
        const float* wp = Wg + (size_t)(col0 + ar) * HD + ac;
        pw0 = *(const float4*)wp;
        pw1 = *(const float4*)(wp + 4);
    }

    f32x4 acc[4] = {};

    for (int s = 0; s < 8; ++s) {
        __syncthreads();
        {
            float fa[8] = {pa0.x, pa0.y, pa0.z, pa0.w, pa1.x, pa1.y, pa1.z, pa1.w};
            float fw[8] = {pw0.x, pw0.y, pw0.z, pw0.w, pw1.x, pw1.y, pw1.z, pw1.w};
            bf16x8 ha, la, hw, lw;
            #pragma unroll
            for (int j = 0; j < 8; ++j) {
                __bf16 av = (__bf16)fa[j];
                ha[j] = av;
                la[j] = (__bf16)(fa[j] - (float)av);
                __bf16 wv = (__bf16)fw[j];
                hw[j] = wv;
                lw[j] = (__bf16)(fw[j] - (float)wv);
            }
            *(bf16x8*)&Ahi_s[ar][ac] = ha;
            *(bf16x8*)&Alo_s[ar][ac] = la;
            *(bf16x8*)&Whi_s[ar][ac] = hw;
            *(bf16x8*)&Wlo_s[ar][ac] = lw;
        }
        __syncthreads();
        if (s < 7) {   // prefetch next K-slab
            const int kc = (s + 1) * 32;
            const float* ap = Ag + ar * HD + kc + ac;
            pa0 = *(const float4*)ap;
            pa1 = *(const float4*)(ap + 4);
            const float* wp = Wg + (size_t)(col0 + ar) * HD + kc + ac;
            pw0 = *(const float4*)wp;
            pw1 = *(const float4*)(wp + 4);
        }
        bf16x8 bh = *(const bf16x8*)&Whi_s[w * 16 + p][quad * 8];
        bf16x8 bl = *(const bf16x8*)&Wlo_s[w * 16 + p][quad * 8];
        #pragma unroll
        for (int mi = 0; mi < 4; ++mi) {
            bf16x8 ah = *(const bf16x8*)&Ahi_s[mi * 16 + p][quad * 8];
            bf16x8 al = *(const bf16x8*)&Alo_s[mi * 16 + p][quad * 8];
            acc[mi] = __builtin_amdgcn_mfma_f32_16x16x32_bf16(ah, bh, acc[mi], 0, 0, 0);
            acc[mi] = __builtin_amdgcn_mfma_f32_16x16x32_bf16(ah, bl, acc[mi], 0, 0, 0);
            acc[mi] = __builtin_amdgcn_mfma_f32_16x16x32_bf16(al, bh, acc[mi], 0, 0, 0);
        }
    }

    // epilogue: C/D layout col=lane&15, row=quad*4+reg
    #pragma unroll
    for (int mi = 0; mi < 4; ++mi) {
        const int H  = col0 + w * 16 + p;
        const int rl = mi * 16 + quad * 4;
        float e0 = fexp2(acc[mi][0] * EXP_SCALE);
        float e1 = fexp2(acc[mi][1] * EXP_SCALE);
        float e2 = fexp2(acc[mi][2] * EXP_SCALE);
        float e3 = fexp2(acc[mi][3] * EXP_SCALE);
        if (isq) {
            float* dst = Eq + (size_t)(row0 + rl) * HD + H;
            dst[0] = e0; dst[HD] = e1; dst[2 * HD] = e2; dst[3 * HD] = e3;
        } else {
            const int kr = row0 - 2048 + rl;
            const int b = kr >> 9, k0 = kr & 511;
            float4 st; st.x = e0; st.y = e1; st.z = e2; st.w = e3;
            *(float4*)(Ekt + ((size_t)b * HD + H) * KLEN + k0) = st;
        }
    }
}

// ---------------- fallback fp32 projection (if ws too small) ----------
__global__ __launch_bounds__(256) void proj_exp_gemm(
    const float* __restrict__ Qin, const float* __restrict__ Kin,
    const float* __restrict__ Wq, const float* __restrict__ Wk,
    float* __restrict__ Eq, float* __restrict__ Ekt)
{
    __shared__ union {
        struct { float a[2][16][68]; float w[2][16][68]; } s;
        float tb[64][65];
    } sh;

    const int t  = threadIdx.x;
    const int tx = t & 15, ty = t >> 4;
    const int bx = blockIdx.x, by = blockIdx.y;
    const bool isq = by < 32;
    const int row0 = isq ? by * 64 : (by - 32) * 64;
    const float* A = isq ? Qin : Kin;
    const float* W = isq ? Wq : Wk;
    const int lrow = t >> 2, ld0 = (t & 3) * 4;
    const float* Ab = A + (row0 + lrow) * HD;
    const float* Wb = W + (bx * 64 + lrow) * HD;

    float4 av = *(const float4*)(Ab + ld0);
    float4 wv = *(const float4*)(Wb + ld0);
    sh.s.a[0][ld0 + 0][lrow] = av.x; sh.s.a[0][ld0 + 1][lrow] = av.y;
    sh.s.a[0][ld0 + 2][lrow] = av.z; sh.s.a[0][ld0 + 3][lrow] = av.w;
    sh.s.w[0][ld0 + 0][lrow] = wv.x; sh.s.w[0][ld0 + 1][lrow] = wv.y;
    sh.s.w[0][ld0 + 2][lrow] = wv.z; sh.s.w[0][ld0 + 3][lrow] = wv.w;

    float acc[4][4] = {};
    int p = 0;
    for (int kc = 0; kc < HD; kc += 16) {
        if (kc + 16 < HD) {
            av = *(const float4*)(Ab + kc + 16 + ld0);
            wv = *(const float4*)(Wb + kc + 16 + ld0);
        }
        __syncthreads();
        if (kc + 16 < HD) {
            const int np = p ^ 1;
            sh.s.a[np][ld0 + 0][lrow] = av.x; sh.s.a[np][ld0 + 1][lrow] = av.y;
            sh.s.a[np][ld0 + 2][lrow] = av.z; sh.s.a[np][ld0 + 3][lrow] = av.w;
            sh.s.w[np][ld0 + 0][lrow] = wv.x; sh.s.w[np][ld0 + 1][lrow] = wv.y;
            sh.s.w[np][ld0 + 2][lrow] = wv.z; sh.s.w[np][ld0 + 3][lrow] = wv.w;
        }
        #pragma unroll
        for (int dd = 0; dd < 16; ++dd) {
            float4 a4 = *(const float4*)&sh.s.a[p][dd][ty * 4];
            float4 w4 = *(const float4*)&sh.s.w[p][dd][tx * 4];
            const float* af = (const float*)&a4;
            const float* wf = (const float*)&w4;
            #pragma unroll
            for (int i = 0; i < 4; ++i)
                #pragma unroll
                for (int j = 0; j < 4; ++j)
                    acc[i][j] = fmaf(af[i], wf[j], acc[i][j]);
        }
        p ^= 1;
    }

    float e[4][4];
    #pragma unroll
    for (int i = 0; i < 4; ++i)
        #pragma unroll
        for (int j = 0; j < 4; ++j)
            e[i][j] = fexp2(acc[i][j] * EXP_SCALE);

    if (isq) {
        float* Cb = Eq + (row0 + ty * 4) * HD + bx * 64 + tx * 4;
        #pragma unroll
        for (int i = 0; i < 4; ++i) {
            float4 st; st.x = e[i][0]; st.y = e[i][1]; st.z = e[i][2]; st.w = e[i][3];
            *(float4*)(Cb + i * HD) = st;
        }
    } else {
        __syncthreads();
        #pragma unroll
        for (int j = 0; j < 4; ++j) {
            float4 st; st.x = e[0][j]; st.y = e[1][j]; st.z = e[2][j]; st.w = e[3][j];
            *(float4*)&sh.tb[tx * 4 + j][ty * 4] = st;
        }
        __syncthreads();
        const int r = t >> 2, c0 = (t & 3) * 16;
        const int b = row0 >> 9, kbase = row0 & 511;
        float* dst = Ekt + ((size_t)b * HD + bx * 64 + r) * KLEN + kbase + c0;
        #pragma unroll
        for (int u = 0; u < 4; ++u) {
            float4 v = *(const float4*)&sh.tb[r][c0 + u * 4];
            *(float4*)(dst + u * 4) = v;
        }
    }
}

// ---------------- fused scores + masked softmax + PV ------------------
// grid 512: blk = qtile*16 + b (4 queries/tile). XCD (blk%8) = b%8 serves
// batches {x, x+8}: Ekt+values+Eq slabs (~2.3 MB) fit that XCD's L2.
// Phase-1 Ekt loads are software-pipelined (register prefetch of the next
// hh-iteration) to overlap L2/LLC latency with the tanh math.
// Wave-uniform skipping of fully-masked k-ranges.
__global__ __launch_bounds__(512, 4) void fused_attn(
    const float* __restrict__ Eq, const float* __restrict__ Ekt,
    const float* __restrict__ values, const float* __restrict__ Wv,
    const int* __restrict__ vlen, float* __restrict__ out)
{
    __shared__ float eq_s[4][HD];
    __shared__ float wv_s[HD];
    __shared__ float sc[4][KLEN];
    __shared__ float ps[4][4][KLEN];   // phase-1 partials; aliased as po[8][4][VD]
    __shared__ float wred[4];

    const int t    = threadIdx.x;
    const int b    = blockIdx.x & 15;
    const int q0   = (blockIdx.x >> 4) * 4;
    const int lane = t & 63;
    const int wid  = t >> 6;
    const int len  = vlen[b];

    {
        const int h = t & 255, rr = t >> 8;
        eq_s[rr][h]     = Eq[(b * QLEN + q0 + rr) * HD + h];
        eq_s[rr + 2][h] = Eq[(b * QLEN + q0 + rr + 2) * HD + h];
        if (t < HD) {
            float w = Wv[t];
            wv_s[t] = w;
            float ws = w;
            #pragma unroll
            for (int off = 32; off > 0; off >>= 1) ws += __shfl_xor(ws, off, 64);
            if (lane == 0) wred[wid] = ws;
        }
    }
    __syncthreads();
    const float wv_sum = wred[0] + wred[1] + wred[2] + wred[3];

    // ---- Phase 1: scores. Wave = (h-slice, k-half); skip masked k-half.
    const int hs    = wid & 3, khalf = wid >> 2;
    if (khalf * 256 < len) {
        const int hbase = hs * 64;
        const int k4    = khalf * 256 + lane * 4;
        const float* ek = Ekt + ((size_t)b * HD + hbase) * KLEN + k4;
        float acc[4][4] = {};
        float4 n0 = *(const float4*)(ek + 0 * KLEN);
        float4 n1 = *(const float4*)(ek + 1 * KLEN);
        float4 n2 = *(const float4*)(ek + 2 * KLEN);
        float4 n3 = *(const float4*)(ek + 3 * KLEN);
        for (int hh = 0; hh < 64; hh += 4) {
            float4 e0 = n0, e1 = n1, e2 = n2, e3 = n3;
            if (hh + 4 < 64) {   // software pipeline: next iteration's loads
                const float* nk = ek + (size_t)(hh + 4) * KLEN;
                n0 = *(const float4*)(nk + 0 * KLEN);
                n1 = *(const float4*)(nk + 1 * KLEN);
                n2 = *(const float4*)(nk + 2 * KLEN);
                n3 = *(const float4*)(nk + 3 * KLEN);
            }
            const float* E0 = (const float*)&e0;
            const float* E1 = (const float*)&e1;
            const float* E2 = (const float*)&e2;
            const float* E3 = (const float*)&e3;
            const float w0 = wv_s[hbase + hh + 0], w1 = wv_s[hbase + hh + 1];
            const float w2 = wv_s[hbase + hh + 2], w3 = wv_s[hbase + hh + 3];
            #pragma unroll
            for (int i = 0; i < 4; ++i) {
                const float a0 = eq_s[i][hbase + hh + 0], a1 = eq_s[i][hbase + hh + 1];
                const float a2 = eq_s[i][hbase + hh + 2], a3 = eq_s[i][hbase + hh + 3];
                #pragma unroll
                for (int j = 0; j < 4; ++j) {
                    float d0 = fmaf(a0, E0[j], 1.f);
                    float d1 = fmaf(a1, E1[j], 1.f);
                    float d2 = fmaf(a2, E2[j], 1.f);
                    float d3 = fmaf(a3, E3[j], 1.f);
                    float d01 = d0 * d1, d23 = d2 * d3;
                    float n01 = fmaf(w1, d0, w0 * d1);
                    float n23 = fmaf(w3, d2, w2 * d3);
                    float top = fmaf(n23, d01, n01 * d23);
                    acc[i][j] = fmaf(top, frcp(d01 * d23), acc[i][j]);
                }
            }
        }
        #pragma unroll
        for (int i = 0; i < 4; ++i) {
            float4 st; st.x = acc[i][0]; st.y = acc[i][1]; st.z = acc[i][2]; st.w = acc[i][3];
            *(float4*)&ps[hs][i][k4] = st;
        }
    }
    __syncthreads();

    {   // reduce 4 h-slices (garbage for masked k: zeroed by softmax below)
        const int q = t >> 7, kk = (t & 127) * 4;
        float4 s0 = *(const float4*)&ps[0][q][kk];
        float4 s1 = *(const float4*)&ps[1][q][kk];
        float4 s2 = *(const float4*)&ps[2][q][kk];
        float4 s3 = *(const float4*)&ps[3][q][kk];
        float4 r;
        r.x = fmaf(-2.f, s0.x + s1.x + s2.x + s3.x, wv_sum);
        r.y = fmaf(-2.f, s0.y + s1.y + s2.y + s3.y, wv_sum);
        r.z = fmaf(-2.f, s0.z + s1.z + s2.z + s3.z, wv_sum);
        r.w = fmaf(-2.f, s0.w + s1.w + s2.w + s3.w, wv_sum);
        *(float4*)&sc[q][kk] = r;
    }
    __syncthreads();

    // ---- Phase 2: masked softmax, wave w (w<4) handles row w.
    if (wid < 4) {
        float s[8];
        float m = -3.0e38f;
        #pragma unroll
        for (int j = 0; j < 8; ++j) {
            int k = lane + j * 64;
            float v = sc[wid][k];
            v = (k < len) ? v : -1.0e6f;
            s[j] = v;
            m = fmaxf(m, v);
        }
        #pragma unroll
        for (int off = 32; off > 0; off >>= 1) m = fmaxf(m, __shfl_xor(m, off, 64));
        float sum = 0.f;
        #pragma unroll
        for (int j = 0; j < 8; ++j) {
            float ev = fexp2(1.4426950408889634f * (s[j] - m));
            s[j] = ev;
            sum += ev;
        }
        #pragma unroll
        for (int off = 32; off > 0; off >>= 1) sum += __shfl_xor(sum, off, 64);
        const float rs = frcp(sum);
        #pragma unroll
        for (int j = 0; j < 8; ++j) sc[wid][lane + j * 64] = s[j] * rs;
    }
    __syncthreads();

    // ---- Phase 3: PV, k-sliced; skip fully-masked slices (zero partials).
    float (*po)[4][VD] = (float (*)[4][VD])ps;
    const int c4 = lane * 4;
    if (wid * 64 < len) {
        const float* vb = values + (size_t)b * KLEN * VD + (size_t)(wid * 64) * VD + c4;
        float o[4][4] = {};
        for (int kk = 0; kk < 64; kk += 4) {
            const int k = wid * 64 + kk;
            float4 pr[4];
            pr[0] = *(const float4*)&sc[0][k];
            pr[1] = *(const float4*)&sc[1][k];
            pr[2] = *(const float4*)&sc[2][k];
            pr[3] = *(const float4*)&sc[3][k];
            #pragma unroll
            for (int j = 0; j < 4; ++j) {
                float4 v4 = *(const float4*)(vb + (size_t)(kk + j) * VD);
                #pragma unroll
                for (int r = 0; r < 4; ++r) {
                    float pj = ((const float*)&pr[r])[j];
                    o[r][0] = fmaf(pj, v4.x, o[r][0]);
                    o[r][1] = fmaf(pj, v4.y, o[r][1]);
                    o[r][2] = fmaf(pj, v4.z, o[r][2]);
                    o[r][3] = fmaf(pj, v4.w, o[r][3]);
                }
            }
        }
        #pragma unroll
        for (int r = 0; r < 4; ++r) {
            float4 st; st.x = o[r][0]; st.y = o[r][1]; st.z = o[r][2]; st.w = o[r][3];
            *(float4*)&po[wid][r][c4] = st;
        }
    } else {
        float4 z; z.x = z.y = z.z = z.w = 0.f;
        #pragma unroll
        for (int r = 0; r < 4; ++r) *(float4*)&po[wid][r][c4] = z;
    }
    __syncthreads();

    #pragma unroll
    for (int u = 0; u < 2; ++u) {
        int idx = t + u * 512;
        int r = idx >> 8, c = idx & 255;
        float s = 0.f;
        #pragma unroll
        for (int sl = 0; sl < 8; ++sl) s += po[sl][r][c];
        out[(b * QLEN + q0 + r) * VD + c] = s;
    }
}

extern "C" void kernel_launch(void* const* d_in, const int* in_sizes, int n_in,
                              void* d_out, int out_size, void* d_ws, size_t ws_size,
                              hipStream_t stream) {
    const float* queries = (const float*)d_in[0];
    const float* keys    = (const float*)d_in[1];
    const float* values  = (const float*)d_in[2];
    const float* Wq      = (const float*)d_in[3];
    const float* Wk      = (const float*)d_in[4];
    const float* Wv      = (const float*)d_in[5];
    const int*   vl      = (const int*)d_in[6];
    float* out = (float*)d_out;

    float* Eq  = (float*)d_ws;                 // [2048][256]        (2 MB)
    float* Ekt = Eq + 2048 * 256;              // [16][256][512]     (8 MB)

    if (ws_size >= 10485760) {
        mfma_proj<<<dim3(4, 160), 256, 0, stream>>>(queries, keys, Wq, Wk, vl, Eq, Ekt);
    } else {
        proj_exp_gemm<<<dim3(4, 160), 256, 0, stream>>>(queries, keys, Wq, Wk, Eq, Ekt);
    }
    fused_attn<<<dim3(512), 512, 0, stream>>>(Eq, Ekt, values, Wv, vl, out);
}